// Round 5
// baseline (1230.748 us; speedup 1.0000x reference)
//
#include <hip/hip_runtime.h>
#include <math.h>

// ---------------------------------------------------------------------------
// Polytope projection via dual PGD, restructured:
//   H = A A^T; eta = 1.8/lambda_max(H) (power iter); M = I - eta*H (sym)
//   r = eta*(x A^T - b); lam <- relu(lam M + r) x29 (lam0 = relu(r));
//   out = x - lam A
// Heavy GEMMs: fp16x2 split (Ootomo, v = hi + lo/2048, 3 MFMAs/product),
// 128x128 block tile, 8 waves = 2x2 spatial (64x64 each) x 2 K-groups
// (wave-split-K: group 0 = K[0,K/2), group 1 = K[K/2,K)), partials combined
// via LDS at the epilogue. mfma_f32_32x32x16_f16, BK=32 per group-step,
// double-buffered LDS per group (4 x 32KB = 128KB), raw s_barrier + counted
// s_waitcnt vmcnt(8), setprio(1) around MFMA cluster, chunked XCD swizzle.
// 512 threads, 1 block/CU -> 2 waves/SIMD (TLP to hide ds_read latency).
// ---------------------------------------------------------------------------

typedef _Float16 f16x8 __attribute__((ext_vector_type(8)));
typedef _Float16 f16x4 __attribute__((ext_vector_type(4)));
typedef float f32x16 __attribute__((ext_vector_type(16)));

#define GLD16(G, L)                                                          \
  __builtin_amdgcn_global_load_lds(                                          \
      (const __attribute__((address_space(1))) void*)(const void*)(G),       \
      (__attribute__((address_space(3))) void*)(void*)(L), 16, 0, 0)

// ---------------- elementwise split kernels ----------------

// n/1024 blocks, 256 thr: f32 -> (hi, lo*2048) f16 pair
__global__ __launch_bounds__(256) void k_split(const float* __restrict__ A,
                                               _Float16* __restrict__ Ah,
                                               _Float16* __restrict__ Al) {
    size_t i4 = ((size_t)blockIdx.x * 256 + threadIdx.x) * 4;
    float4 v = *(const float4*)(A + i4);
    float va[4] = {v.x, v.y, v.z, v.w};
    f16x4 hh, ll;
#pragma unroll
    for (int e = 0; e < 4; ++e) {
        _Float16 h = (_Float16)va[e];
        hh[e] = h;
        ll[e] = (_Float16)((va[e] - (float)h) * 2048.f);
    }
    *(f16x4*)(Ah + i4) = hh;
    *(f16x4*)(Al + i4) = ll;
}

// M = I - eta*H, split (m=1024 hardcoded row length)
__global__ __launch_bounds__(256) void k_makeM(const float* __restrict__ H,
                                               const float* __restrict__ eta_p,
                                               _Float16* __restrict__ Mh,
                                               _Float16* __restrict__ Ml) {
    float eta = eta_p[0];
    size_t i4 = ((size_t)blockIdx.x * 256 + threadIdx.x) * 4;
    float4 v = *(const float4*)(H + i4);
    float va[4] = {v.x, v.y, v.z, v.w};
    int row = (int)(i4 >> 10);
    int col0 = (int)(i4 & 1023);
    f16x4 hh, ll;
#pragma unroll
    for (int e = 0; e < 4; ++e) {
        float mv = ((col0 + e) == row ? 1.f : 0.f) - eta * va[e];
        _Float16 h = (_Float16)mv;
        hh[e] = h;
        ll[e] = (_Float16)((mv - (float)h) * 2048.f);
    }
    *(f16x4*)(Mh + i4) = hh;
    *(f16x4*)(Ml + i4) = ll;
}

// A [1024,1024] -> A^T split via 32x32 LDS tiles
__global__ __launch_bounds__(256) void k_tsplit(const float* __restrict__ A,
                                                _Float16* __restrict__ Th,
                                                _Float16* __restrict__ Tl) {
    __shared__ float ts[32][33];
    int i0 = blockIdx.x * 32, j0 = blockIdx.y * 32;
    int tr = threadIdx.x >> 3, tc4 = (threadIdx.x & 7) * 4;
    float4 v = *(const float4*)(A + (size_t)(i0 + tr) * 1024 + j0 + tc4);
    ts[tr][tc4] = v.x; ts[tr][tc4 + 1] = v.y;
    ts[tr][tc4 + 2] = v.z; ts[tr][tc4 + 3] = v.w;
    __syncthreads();
    f16x4 hh, ll;
#pragma unroll
    for (int e = 0; e < 4; ++e) {
        float x = ts[tc4 + e][tr];
        _Float16 h = (_Float16)x;
        hh[e] = h;
        ll[e] = (_Float16)((x - (float)h) * 2048.f);
    }
    *(f16x4*)(Th + (size_t)(j0 + tr) * 1024 + i0 + tc4) = hh;
    *(f16x4*)(Tl + (size_t)(j0 + tr) * 1024 + i0 + tc4) = ll;
}

// ---------------- power iteration on H ----------------

// u0 = A * ones / sqrt(1024)
__global__ __launch_bounds__(256) void k_u0(const float* __restrict__ A,
                                            float* __restrict__ u) {
    int r = blockIdx.x * 16 + (threadIdx.x >> 4);
    int gq = threadIdx.x & 15;
    const float* ar = A + (size_t)r * 1024;
    float s = 0.f;
    for (int c = gq * 4; c < 1024; c += 64) {
        float4 v = *(const float4*)(ar + c);
        s += v.x + v.y + v.z + v.w;
    }
    s += __shfl_xor(s, 1, 16); s += __shfl_xor(s, 2, 16);
    s += __shfl_xor(s, 4, 16); s += __shfl_xor(s, 8, 16);
    if (gq == 0) u[r] = s * 0.03125f;
}

// wout = H * (win / (||win|| + 1e-12));  grid 256, 4 rows/block (1 wave/row)
__global__ __launch_bounds__(256) void k_pmv(const float* __restrict__ H,
                                             const float* __restrict__ win,
                                             float* __restrict__ wout) {
    __shared__ float red[256];
    int t = threadIdx.x;
    float4 v = *(const float4*)(win + t * 4);
    red[t] = v.x * v.x + v.y * v.y + v.z * v.z + v.w * v.w;
    __syncthreads();
    for (int o = 128; o > 0; o >>= 1) {
        if (t < o) red[t] += red[t + o];
        __syncthreads();
    }
    float inv = 1.f / (sqrtf(red[0]) + 1e-12f);
    int row = blockIdx.x * 4 + (t >> 6);
    int lane = t & 63;
    const float* hr = H + (size_t)row * 1024;
    float s = 0.f;
#pragma unroll
    for (int seg = 0; seg < 4; ++seg) {
        float4 hv = *(const float4*)(hr + seg * 256 + lane * 4);
        float4 uv = *(const float4*)(win + seg * 256 + lane * 4);
        s += hv.x * uv.x + hv.y * uv.y + hv.z * uv.z + hv.w * uv.w;
    }
#pragma unroll
    for (int k = 1; k < 64; k <<= 1) s += __shfl_xor(s, k);
    if (lane == 0) wout[row] = s * inv;
}

// eta = 1.8*(w9.w10) / ((||w9||+1e-12) * (w10.w10))
__global__ __launch_bounds__(256) void k_eta3(const float* __restrict__ w9,
                                              const float* __restrict__ w10,
                                              float* __restrict__ eta) {
    __shared__ float r99[256], r910[256], r1010[256];
    int t = threadIdx.x;
    float4 a = *(const float4*)(w9 + t * 4);
    float4 b = *(const float4*)(w10 + t * 4);
    r99[t] = a.x * a.x + a.y * a.y + a.z * a.z + a.w * a.w;
    r910[t] = a.x * b.x + a.y * b.y + a.z * b.z + a.w * b.w;
    r1010[t] = b.x * b.x + b.y * b.y + b.z * b.z + b.w * b.w;
    __syncthreads();
    for (int o = 128; o > 0; o >>= 1) {
        if (t < o) {
            r99[t] += r99[t + o];
            r910[t] += r910[t + o];
            r1010[t] += r1010[t + o];
        }
        __syncthreads();
    }
    if (t == 0)
        eta[0] = 1.8f * r910[0] / ((sqrtf(r99[0]) + 1e-12f) * r1010[0]);
}

// ---------------- fp16x2 split NT MFMA GEMM, wave-split-K ----------------
// C[i][j] = sum_k Aop[i][k]*Bop[j][k].  Requires Kd % 64 == 0.
// EPI 0: fout = acc                          (H)
// EPI 1: rv = eta*(acc - b[j]) -> fout; lam0 = relu(rv) split
// EPI 2: lam = relu(acc + raux) split        (iteration)
// EPI 3: fout = raux - acc                   (final out; raux = x)

template <int EPI>
__global__ __launch_bounds__(512, 1) void k_mm4(
    const _Float16* __restrict__ Agh, const _Float16* __restrict__ Agl,
    const _Float16* __restrict__ Bgh, const _Float16* __restrict__ Bgl,
    int Kd, int Nd,
    const float* __restrict__ eta_p, const float* __restrict__ bvec,
    const float* __restrict__ raux, float* __restrict__ fout,
    _Float16* __restrict__ lamh, _Float16* __restrict__ laml) {
    __shared__ __align__(16) char lds[131072];  // 4 x 32KB stage buffers

    const int t = threadIdx.x;
    const int wid = t >> 6, lane = t & 63;
    const int kg = t >> 8;              // K-group: waves 0-3 -> 0, 4-7 -> 1
    const int ws = wid & 3;             // spatial wave 0..3 (2x2)
    const int wsr = ws >> 1, wsc = ws & 1;
    const int l31 = lane & 31, g2 = lane >> 5;

    // chunked bijective XCD swizzle (gridDim.x % 8 == 0)
    const int gx = gridDim.x, gy = gridDim.y;
    const int id = blockIdx.x + blockIdx.y * gx;
    const int xcd = id & 7, q = id >> 3;
    const int rowBase = (xcd * (gx >> 3) + q / gy) * 128;
    const int colBase = (q % gy) * 128;

    // staging source (pre-swizzled so linear LDS dest holds swizzled layout)
    const int t2 = t & 255;
    const int w2 = t2 >> 6;              // wave-in-group (uniform per wave)
    const int srow = t2 >> 3;            // 0..31
    const int slot = t2 & 7;             // 16B slot within 128B row
    const int jch = slot ^ (srow & 7);   // logical chunk at this slot
    const int kch = (jch & 3) * 8;       // k element offset within h/l half
    const _Float16* srcA =
        (jch >= 4 ? Agl : Agh) + (size_t)(rowBase + srow) * Kd + kch;
    const _Float16* srcB =
        (jch >= 4 ? Bgl : Bgh) + (size_t)(colBase + srow) * Kd + kch;
    const size_t qStep = (size_t)32 * Kd;
    const size_t kSBase = (size_t)kg * (Kd >> 1);  // this group's K origin

    // 8 global_load_lds per thread per STAGE (4 A + 4 B), into buf[kg][P]
#define STAGE(P, S)                                                          \
    {                                                                        \
        _Pragma("unroll") for (int qq = 0; qq < 4; ++qq) {                   \
            GLD16(srcA + kSBase + (size_t)(S) * 32 + qq * qStep,             \
                  lds + (((kg << 1) | (P)) << 15) + qq * 4096 + w2 * 1024);  \
            GLD16(srcB + kSBase + (size_t)(S) * 32 + qq * qStep,             \
                  lds + (((kg << 1) | (P)) << 15) + 16384 + qq * 4096 +      \
                      w2 * 1024);                                            \
        }                                                                    \
    }

    f32x16 acch[2][2], accm[2][2];
#pragma unroll
    for (int m2 = 0; m2 < 2; ++m2)
#pragma unroll
        for (int n2 = 0; n2 < 2; ++n2) {
            acch[m2][n2] = (f32x16)0.f;
            accm[m2][n2] = (f32x16)0.f;
        }

    STAGE(0, 0);  // 8 loads in flight per wave

    const int NS2 = Kd >> 6;  // macro-steps (each group does BK=32 per step)
    for (int s = 0; s < NS2; ++s) {
        const int p = s & 1;
        if (s + 1 < NS2) {
            STAGE(p ^ 1, s + 1);  // 16 in flight
            asm volatile("s_waitcnt vmcnt(8)" ::: "memory");  // oldest 8 done
        } else {
            asm volatile("s_waitcnt vmcnt(0)" ::: "memory");
        }
        asm volatile("s_barrier" ::: "memory");  // buf[kg][p] ready

        const char* base = lds + (((kg << 1) | p) << 15);
        __builtin_amdgcn_s_setprio(1);
#pragma unroll
        for (int ksub = 0; ksub < 2; ++ksub) {
            const int j = ksub * 2 + g2;
            f16x8 ah[2], al[2], bh[2], bl[2];
#pragma unroll
            for (int m2 = 0; m2 < 2; ++m2) {
                int row = wsr * 64 + m2 * 32 + l31;
                const char* rp = base + row * 128;
                ah[m2] = *(const f16x8*)(rp + ((j ^ (row & 7)) << 4));
                al[m2] = *(const f16x8*)(rp + (((j + 4) ^ (row & 7)) << 4));
            }
#pragma unroll
            for (int n2 = 0; n2 < 2; ++n2) {
                int row = wsc * 64 + n2 * 32 + l31;
                const char* rp = base + 16384 + row * 128;
                bh[n2] = *(const f16x8*)(rp + ((j ^ (row & 7)) << 4));
                bl[n2] = *(const f16x8*)(rp + (((j + 4) ^ (row & 7)) << 4));
            }
#pragma unroll
            for (int m2 = 0; m2 < 2; ++m2)
#pragma unroll
                for (int n2 = 0; n2 < 2; ++n2) {
                    acch[m2][n2] = __builtin_amdgcn_mfma_f32_32x32x16_f16(
                        ah[m2], bh[n2], acch[m2][n2], 0, 0, 0);
                    accm[m2][n2] = __builtin_amdgcn_mfma_f32_32x32x16_f16(
                        ah[m2], bl[n2], accm[m2][n2], 0, 0, 0);
                    accm[m2][n2] = __builtin_amdgcn_mfma_f32_32x32x16_f16(
                        al[m2], bh[n2], accm[m2][n2], 0, 0, 0);
                }
        }
        __builtin_amdgcn_s_setprio(0);
        // protect buf[kg][p] before next iteration's STAGE overwrites it
        asm volatile("s_barrier" ::: "memory");
    }
#undef STAGE

    // ---- combine K-groups via LDS; C frag: col=l31, row=(reg&3)+8*(reg>>2)+4*g2
    const float cl = 4.8828125e-4f;  // 2^-11
    float* xch = (float*)lds;        // 4 spatial regions x 16KB (64x64 f32)
    if (kg == 1) {
#pragma unroll
        for (int m2 = 0; m2 < 2; ++m2)
#pragma unroll
            for (int n2 = 0; n2 < 2; ++n2) {
                const int lc = n2 * 32 + l31;
#pragma unroll
                for (int reg = 0; reg < 16; ++reg) {
                    const int lr = m2 * 32 + (reg & 3) + ((reg >> 2) << 3) +
                                   (g2 << 2);
                    xch[(ws << 12) + lr * 64 + lc] =
                        acch[m2][n2][reg] + accm[m2][n2][reg] * cl;
                }
            }
    }
    __syncthreads();
    if (kg == 0) {
        const float etav = (EPI == 1) ? eta_p[0] : 0.f;
#pragma unroll
        for (int m2 = 0; m2 < 2; ++m2)
#pragma unroll
            for (int n2 = 0; n2 < 2; ++n2) {
                const int lc = n2 * 32 + l31;
                const int col = colBase + wsc * 64 + lc;
#pragma unroll
                for (int reg = 0; reg < 16; ++reg) {
                    const int lr = m2 * 32 + (reg & 3) + ((reg >> 2) << 3) +
                                   (g2 << 2);
                    const int row = rowBase + wsr * 64 + lr;
                    const size_t idx = (size_t)row * Nd + col;
                    float val = acch[m2][n2][reg] + accm[m2][n2][reg] * cl +
                                xch[(ws << 12) + lr * 64 + lc];
                    if (EPI == 0) {
                        fout[idx] = val;
                    } else if (EPI == 1) {
                        float rv = etav * (val - bvec[col]);
                        fout[idx] = rv;
                        float lv = fmaxf(rv, 0.f);
                        _Float16 h = (_Float16)lv;
                        lamh[idx] = h;
                        laml[idx] = (_Float16)((lv - (float)h) * 2048.f);
                    } else if (EPI == 2) {
                        float lv = fmaxf(val + raux[idx], 0.f);
                        _Float16 h = (_Float16)lv;
                        lamh[idx] = h;
                        laml[idx] = (_Float16)((lv - (float)h) * 2048.f);
                    } else {
                        fout[idx] = raux[idx] - val;
                    }
                }
            }
    }
}

// ---------------------------------------------------------------------------

extern "C" void kernel_launch(void* const* d_in, const int* in_sizes, int n_in,
                              void* d_out, int out_size, void* d_ws, size_t ws_size,
                              hipStream_t stream) {
    const float* x = (const float*)d_in[0];  // [B, d] = [4096, 1024]
    const float* A = (const float*)d_in[1];  // [m, d] = [1024, 1024]
    const float* b = (const float*)d_in[2];  // [m]

    const int m = in_sizes[2];           // 1024
    const int dd = in_sizes[1] / m;      // 1024
    const int Bn = in_sizes[0] / dd;     // 4096
    float* out = (float*)d_out;

    // workspace layout (<= 60 MB + 16 KB; x-split region is reused as l1,
    // H region is reused for A^T split after the iterations)
    const size_t MB = 1u << 20;
    char* w8 = (char*)d_ws;
    float* eta = (float*)w8;                       // 256 B
    float* wA = (float*)(w8 + 256);                // 4 KB
    float* wB = (float*)(w8 + 256 + 4096);         // 4 KB
    char* base = w8 + 16384;
    float* H = (float*)base;                       // 4 MB (later: AT split)
    _Float16* ATh = (_Float16*)base;               //   2 MB (aliases H)
    _Float16* ATl = (_Float16*)(base + 2 * MB);    //   2 MB (aliases H)
    _Float16* Mh = (_Float16*)(base + 4 * MB);     // 2 MB
    _Float16* Ml = (_Float16*)(base + 6 * MB);     // 2 MB
    _Float16* Ah = (_Float16*)(base + 8 * MB);     // 2 MB
    _Float16* Al = (_Float16*)(base + 10 * MB);    // 2 MB
    _Float16* xh = (_Float16*)(base + 12 * MB);    // 8 MB (later: l1h)
    _Float16* xl = (_Float16*)(base + 20 * MB);    // 8 MB (later: l1l)
    float* r = (float*)(base + 28 * MB);           // 16 MB
    _Float16* l0h = (_Float16*)(base + 44 * MB);   // 8 MB
    _Float16* l0l = (_Float16*)(base + 52 * MB);   // 8 MB
    _Float16* l1h = xh;
    _Float16* l1l = xl;

    // ---- split A and x ----
    k_split<<<(m * dd) / 1024, 256, 0, stream>>>(A, Ah, Al);
    k_split<<<(Bn * dd) / 1024, 256, 0, stream>>>(x, xh, xl);

    // ---- H = A A^T ----
    k_mm4<0><<<dim3(m / 128, m / 128), 512, 0, stream>>>(
        Ah, Al, Ah, Al, dd, m, nullptr, nullptr, nullptr, H, nullptr, nullptr);

    // ---- power iteration: eta = 1.8/lambda_max(H) ----
    k_u0<<<m / 16, 256, 0, stream>>>(A, wA);
    for (int it = 0; it < 5; ++it) {
        k_pmv<<<m / 4, 256, 0, stream>>>(H, wA, wB);
        k_pmv<<<m / 4, 256, 0, stream>>>(H, wB, wA);
    }
    // w9 in wB, w10 in wA
    k_eta3<<<1, 256, 0, stream>>>(wB, wA, eta);

    // ---- M = I - eta*H (split f16) ----
    k_makeM<<<(m * m) / 1024, 256, 0, stream>>>(H, eta, Mh, Ml);

    // ---- r = eta*(x A^T - b); lam0 = relu(r) split ----
    k_mm4<1><<<dim3(Bn / 128, m / 128), 512, 0, stream>>>(
        xh, xl, Ah, Al, dd, m, eta, b, nullptr, r, l0h, l0l);

    // ---- 29 iterations: lam <- relu(lam M + r) ----
    const _Float16 *pih = l0h, *pil = l0l;
    _Float16 *poh = l1h, *pol = l1l;
    for (int it = 0; it < 29; ++it) {
        k_mm4<2><<<dim3(Bn / 128, m / 128), 512, 0, stream>>>(
            pih, pil, Mh, Ml, m, m, nullptr, nullptr, r, nullptr, poh, pol);
        const _Float16* th = pih;
        const _Float16* tl = pil;
        pih = poh; pil = pol;
        poh = (_Float16*)th; pol = (_Float16*)tl;
    }
    // 29 steps: final lam in l1 (x-split no longer needed)

    // ---- A^T split into old H region; out = x - lam A ----
    k_tsplit<<<dim3(m / 32, dd / 32), 256, 0, stream>>>(A, ATh, ATl);
    k_mm4<3><<<dim3(Bn / 128, dd / 128), 512, 0, stream>>>(
        pih, pil, ATh, ATl, m, dd, nullptr, nullptr, x, out, nullptr, nullptr);
}

// Round 6
// 1039.153 us; speedup vs baseline: 1.1844x; 1.1844x over previous
//
#include <hip/hip_runtime.h>
#include <math.h>

// ---------------------------------------------------------------------------
// Polytope projection via dual PGD, restructured:
//   H = A A^T; eta = 1.8/lambda_max(H) (power iter)
//   Moff = -eta*H with ZERO diagonal (f16-hi only; A has unit rows so
//          M_jj = 1-eta exactly -> applied exactly in the epilogue)
//   r = eta*(x A^T - b); lam <- relu(lam@Moff + (1-eta)*lam + r) x29
//   out = x - lam A
// GEMM kernel k_mm5<EPI,FULLB>: tile 64x128, 4 waves (32x64 each),
// mfma_f32_32x32x16_f16, BK=32 dbuf, counted s_waitcnt vmcnt(N) + raw
// s_barrier (R4-proven), setprio around MFMA. grid (N/128, M/64): with
// gridDim.x=8, dispatch id%8 = col-tile = XCD -> M-panel L2 locality.
// FULLB (r/H/out): 3-MFMA Ootomo split both sides.
// !FULLB (iteration): 2-MFMA (lam full split x Mh f16) + exact diag.
// ---------------------------------------------------------------------------

typedef _Float16 f16x8 __attribute__((ext_vector_type(8)));
typedef _Float16 f16x4 __attribute__((ext_vector_type(4)));
typedef float f32x16 __attribute__((ext_vector_type(16)));

#define GLD16(G, L)                                                          \
  __builtin_amdgcn_global_load_lds(                                          \
      (const __attribute__((address_space(1))) void*)(const void*)(G),       \
      (__attribute__((address_space(3))) void*)(void*)(L), 16, 0, 0)

// ---------------- elementwise split kernels ----------------

__global__ __launch_bounds__(256) void k_split(const float* __restrict__ A,
                                               _Float16* __restrict__ Ah,
                                               _Float16* __restrict__ Al) {
    size_t i4 = ((size_t)blockIdx.x * 256 + threadIdx.x) * 4;
    float4 v = *(const float4*)(A + i4);
    float va[4] = {v.x, v.y, v.z, v.w};
    f16x4 hh, ll;
#pragma unroll
    for (int e = 0; e < 4; ++e) {
        _Float16 h = (_Float16)va[e];
        hh[e] = h;
        ll[e] = (_Float16)((va[e] - (float)h) * 2048.f);
    }
    *(f16x4*)(Ah + i4) = hh;
    *(f16x4*)(Al + i4) = ll;
}

// Moff = -eta*H, diag forced to 0, f16-hi only (m=1024 row length)
__global__ __launch_bounds__(256) void k_makeMoff(const float* __restrict__ H,
                                                  const float* __restrict__ eta_p,
                                                  _Float16* __restrict__ Mh) {
    float eta = eta_p[0];
    size_t i4 = ((size_t)blockIdx.x * 256 + threadIdx.x) * 4;
    float4 v = *(const float4*)(H + i4);
    float va[4] = {v.x, v.y, v.z, v.w};
    int row = (int)(i4 >> 10);
    int col0 = (int)(i4 & 1023);
    f16x4 hh;
#pragma unroll
    for (int e = 0; e < 4; ++e) {
        float mv = ((col0 + e) == row) ? 0.f : (-eta * va[e]);
        hh[e] = (_Float16)mv;
    }
    *(f16x4*)(Mh + i4) = hh;
}

// A [1024,1024] -> A^T split via 32x32 LDS tiles
__global__ __launch_bounds__(256) void k_tsplit(const float* __restrict__ A,
                                                _Float16* __restrict__ Th,
                                                _Float16* __restrict__ Tl) {
    __shared__ float ts[32][33];
    int i0 = blockIdx.x * 32, j0 = blockIdx.y * 32;
    int tr = threadIdx.x >> 3, tc4 = (threadIdx.x & 7) * 4;
    float4 v = *(const float4*)(A + (size_t)(i0 + tr) * 1024 + j0 + tc4);
    ts[tr][tc4] = v.x; ts[tr][tc4 + 1] = v.y;
    ts[tr][tc4 + 2] = v.z; ts[tr][tc4 + 3] = v.w;
    __syncthreads();
    f16x4 hh, ll;
#pragma unroll
    for (int e = 0; e < 4; ++e) {
        float x = ts[tc4 + e][tr];
        _Float16 h = (_Float16)x;
        hh[e] = h;
        ll[e] = (_Float16)((x - (float)h) * 2048.f);
    }
    *(f16x4*)(Th + (size_t)(j0 + tr) * 1024 + i0 + tc4) = hh;
    *(f16x4*)(Tl + (size_t)(j0 + tr) * 1024 + i0 + tc4) = ll;
}

// ---------------- power iteration on H ----------------

__global__ __launch_bounds__(256) void k_u0(const float* __restrict__ A,
                                            float* __restrict__ u) {
    int r = blockIdx.x * 16 + (threadIdx.x >> 4);
    int gq = threadIdx.x & 15;
    const float* ar = A + (size_t)r * 1024;
    float s = 0.f;
    for (int c = gq * 4; c < 1024; c += 64) {
        float4 v = *(const float4*)(ar + c);
        s += v.x + v.y + v.z + v.w;
    }
    s += __shfl_xor(s, 1, 16); s += __shfl_xor(s, 2, 16);
    s += __shfl_xor(s, 4, 16); s += __shfl_xor(s, 8, 16);
    if (gq == 0) u[r] = s * 0.03125f;
}

// wout = H * (win / (||win|| + 1e-12));  grid 256, 4 rows/block
__global__ __launch_bounds__(256) void k_pmv(const float* __restrict__ H,
                                             const float* __restrict__ win,
                                             float* __restrict__ wout) {
    __shared__ float red[256];
    int t = threadIdx.x;
    float4 v = *(const float4*)(win + t * 4);
    red[t] = v.x * v.x + v.y * v.y + v.z * v.z + v.w * v.w;
    __syncthreads();
    for (int o = 128; o > 0; o >>= 1) {
        if (t < o) red[t] += red[t + o];
        __syncthreads();
    }
    float inv = 1.f / (sqrtf(red[0]) + 1e-12f);
    int row = blockIdx.x * 4 + (t >> 6);
    int lane = t & 63;
    const float* hr = H + (size_t)row * 1024;
    float s = 0.f;
#pragma unroll
    for (int seg = 0; seg < 4; ++seg) {
        float4 hv = *(const float4*)(hr + seg * 256 + lane * 4);
        float4 uv = *(const float4*)(win + seg * 256 + lane * 4);
        s += hv.x * uv.x + hv.y * uv.y + hv.z * uv.z + hv.w * uv.w;
    }
#pragma unroll
    for (int k = 1; k < 64; k <<= 1) s += __shfl_xor(s, k);
    if (lane == 0) wout[row] = s * inv;
}

// eta = 1.8*(w9.w10) / ((||w9||+1e-12) * (w10.w10))
__global__ __launch_bounds__(256) void k_eta3(const float* __restrict__ w9,
                                              const float* __restrict__ w10,
                                              float* __restrict__ eta) {
    __shared__ float r99[256], r910[256], r1010[256];
    int t = threadIdx.x;
    float4 a = *(const float4*)(w9 + t * 4);
    float4 b = *(const float4*)(w10 + t * 4);
    r99[t] = a.x * a.x + a.y * a.y + a.z * a.z + a.w * a.w;
    r910[t] = a.x * b.x + a.y * b.y + a.z * b.z + a.w * b.w;
    r1010[t] = b.x * b.x + b.y * b.y + b.z * b.z + b.w * b.w;
    __syncthreads();
    for (int o = 128; o > 0; o >>= 1) {
        if (t < o) {
            r99[t] += r99[t + o];
            r910[t] += r910[t + o];
            r1010[t] += r1010[t + o];
        }
        __syncthreads();
    }
    if (t == 0)
        eta[0] = 1.8f * r910[0] / ((sqrtf(r99[0]) + 1e-12f) * r1010[0]);
}

// ---------------- fp16x2 split NT MFMA GEMM (tile 64x128) ----------------
// C[i][j] = sum_k Aop[i][k]*Bop[j][k].
// EPI 0: fout = acc                          (H; FULLB)
// EPI 1: rv = eta*(acc - b[j]) -> fout; lam0 = relu(rv) split (FULLB)
// EPI 2: lam = relu(acc + (1-eta)*lamin + r) split   (iteration; !FULLB,
//         lamin re-read from Agh/Agl at [i][j])
// EPI 3: fout = raux - acc                   (final out; raux = x; FULLB)

template <int EPI, bool FB>
__global__ __launch_bounds__(256, 2) void k_mm5(
    const _Float16* __restrict__ Agh, const _Float16* __restrict__ Agl,
    const _Float16* __restrict__ Bgh, const _Float16* __restrict__ Bgl,
    int Kd, int Nd,
    const float* __restrict__ eta_p, const float* __restrict__ bvec,
    const float* __restrict__ raux, float* __restrict__ fout,
    _Float16* __restrict__ lamh, _Float16* __restrict__ laml) {
    constexpr int BROW = FB ? 128 : 64;           // bytes per B-tile row
    constexpr int BUFB = 8192 + 128 * BROW;       // one dbuf buffer
    constexpr int NB = FB ? 4 : 2;                // B gld_lds per thread
    constexpr int VM = 2 + NB;                    // loads in flight per step
    __shared__ __align__(16) char lds[2 * BUFB];

    const int t = threadIdx.x;
    const int wid = t >> 6, lane = t & 63;
    const int wsr = wid >> 1, wsc = wid & 1;      // 2x2 waves over 64x128
    const int l31 = lane & 31, g2 = lane >> 5;

    const int rowBase = blockIdx.y * 64;          // M dimension
    const int colBase = blockIdx.x * 128;         // N dimension (8 col tiles)

    // ---- staging sources (pre-swizzled; LDS dest linear) ----
    // A: 64 rows x 128B (slots 0-3 = hi k-chunks, 4-7 = lo; XOR row&7)
    const _Float16* aP[2];
#pragma unroll
    for (int s = 0; s < 2; ++s) {
        int q = s * 256 + t, row = q >> 3, slot = q & 7;
        int jch = slot ^ (row & 7);
        aP[s] = (jch >= 4 ? Agl : Agh) + (size_t)(rowBase + row) * Kd +
                (jch & 3) * 8;
    }
    // B: 128 rows; FULL: 128B rows as A; LITE: 64B rows (4 hi slots,
    // XOR (row>>1)&3 for bank spread)
    const _Float16* bP[NB];
#pragma unroll
    for (int s = 0; s < NB; ++s) {
        int q = s * 256 + t;
        if (FB) {
            int row = q >> 3, slot = q & 7;
            int jch = slot ^ (row & 7);
            bP[s] = (jch >= 4 ? Bgl : Bgh) + (size_t)(colBase + row) * Kd +
                    (jch & 3) * 8;
        } else {
            int row = q >> 2, slot = q & 3;
            int jch = slot ^ ((row >> 1) & 3);
            bP[s] = Bgh + (size_t)(colBase + row) * Kd + jch * 8;
        }
    }

#define STAGE(P, KO)                                                         \
    {                                                                        \
        _Pragma("unroll") for (int s = 0; s < 2; ++s)                        \
            GLD16(aP[s] + (KO), lds + (P)*BUFB + (s * 256 + t) * 16);        \
        _Pragma("unroll") for (int s = 0; s < NB; ++s)                       \
            GLD16(bP[s] + (KO), lds + (P)*BUFB + 8192 + (s * 256 + t) * 16); \
    }

    f32x16 acch[2], accm[2];
#pragma unroll
    for (int n2 = 0; n2 < 2; ++n2) {
        acch[n2] = (f32x16)0.f;
        accm[n2] = (f32x16)0.f;
    }

    STAGE(0, 0);

    const int NS = Kd >> 5;
    for (int ks = 0; ks < NS; ++ks) {
        const int p = ks & 1;
        if (ks + 1 < NS) {
            STAGE(p ^ 1, (ks + 1) << 5);
            asm volatile("s_waitcnt vmcnt(%0)" ::"i"(VM) : "memory");
        } else {
            asm volatile("s_waitcnt vmcnt(0)" ::: "memory");
        }
        asm volatile("s_barrier" ::: "memory");

        const char* ab = lds + p * BUFB;
        const char* bb = ab + 8192;
        __builtin_amdgcn_s_setprio(1);
#pragma unroll
        for (int ksub = 0; ksub < 2; ++ksub) {
            const int j = ksub * 2 + g2;
            const int rowA = wsr * 32 + l31;
            const char* rpA = ab + rowA * 128;
            f16x8 ah = *(const f16x8*)(rpA + ((j ^ (rowA & 7)) << 4));
            f16x8 al = *(const f16x8*)(rpA + (((j + 4) ^ (rowA & 7)) << 4));
            f16x8 bh[2], bl[2];
#pragma unroll
            for (int n2 = 0; n2 < 2; ++n2) {
                int rowB = wsc * 64 + n2 * 32 + l31;
                const char* rpB = bb + rowB * BROW;
                if (FB) {
                    bh[n2] = *(const f16x8*)(rpB + ((j ^ (rowB & 7)) << 4));
                    bl[n2] =
                        *(const f16x8*)(rpB + (((j + 4) ^ (rowB & 7)) << 4));
                } else {
                    bh[n2] =
                        *(const f16x8*)(rpB + ((j ^ ((rowB >> 1) & 3)) << 4));
                }
            }
#pragma unroll
            for (int n2 = 0; n2 < 2; ++n2) {
                acch[n2] = __builtin_amdgcn_mfma_f32_32x32x16_f16(
                    ah, bh[n2], acch[n2], 0, 0, 0);
                if (FB) {
                    accm[n2] = __builtin_amdgcn_mfma_f32_32x32x16_f16(
                        ah, bl[n2], accm[n2], 0, 0, 0);
                    accm[n2] = __builtin_amdgcn_mfma_f32_32x32x16_f16(
                        al, bh[n2], accm[n2], 0, 0, 0);
                } else {
                    accm[n2] = __builtin_amdgcn_mfma_f32_32x32x16_f16(
                        al, bh[n2], accm[n2], 0, 0, 0);
                }
            }
        }
        __builtin_amdgcn_s_setprio(0);
        asm volatile("s_barrier" ::: "memory");
    }
#undef STAGE

    // ---- epilogue; C frag: col = lane&31, row = (reg&3)+8*(reg>>2)+4*g2
    const float cl = 4.8828125e-4f;  // 2^-11
    const float etav = (EPI == 1 || EPI == 2) ? eta_p[0] : 0.f;
#pragma unroll
    for (int n2 = 0; n2 < 2; ++n2) {
        const int col = colBase + wsc * 64 + n2 * 32 + l31;
#pragma unroll
        for (int reg = 0; reg < 16; ++reg) {
            const int row = rowBase + wsr * 32 + (reg & 3) +
                            ((reg >> 2) << 3) + (g2 << 2);
            const size_t idx = (size_t)row * Nd + col;
            float val = acch[n2][reg] + accm[n2][reg] * cl;
            if (EPI == 0) {
                fout[idx] = val;
            } else if (EPI == 1) {
                float rv = etav * (val - bvec[col]);
                fout[idx] = rv;
                float lv = fmaxf(rv, 0.f);
                _Float16 h = (_Float16)lv;
                lamh[idx] = h;
                laml[idx] = (_Float16)((lv - (float)h) * 2048.f);
            } else if (EPI == 2) {
                float li = (float)Agh[idx] + (float)Agl[idx] * cl;
                float lv = fmaxf(val + (1.f - etav) * li + raux[idx], 0.f);
                _Float16 h = (_Float16)lv;
                lamh[idx] = h;
                laml[idx] = (_Float16)((lv - (float)h) * 2048.f);
            } else {
                fout[idx] = raux[idx] - val;
            }
        }
    }
}

// ---------------------------------------------------------------------------

extern "C" void kernel_launch(void* const* d_in, const int* in_sizes, int n_in,
                              void* d_out, int out_size, void* d_ws, size_t ws_size,
                              hipStream_t stream) {
    const float* x = (const float*)d_in[0];  // [B, d] = [4096, 1024]
    const float* A = (const float*)d_in[1];  // [m, d] = [1024, 1024]
    const float* b = (const float*)d_in[2];  // [m]

    const int m = in_sizes[2];           // 1024
    const int dd = in_sizes[1] / m;      // 1024
    const int Bn = in_sizes[0] / dd;     // 4096
    float* out = (float*)d_out;

    // workspace layout (x-split region reused as l1; H reused for A^T split)
    const size_t MB = 1u << 20;
    char* w8 = (char*)d_ws;
    float* eta = (float*)w8;                       // 256 B
    float* wA = (float*)(w8 + 256);                // 4 KB
    float* wB = (float*)(w8 + 256 + 4096);         // 4 KB
    char* base = w8 + 16384;
    float* H = (float*)base;                       // 4 MB (later: AT split)
    _Float16* ATh = (_Float16*)base;               //   2 MB (aliases H)
    _Float16* ATl = (_Float16*)(base + 2 * MB);    //   2 MB (aliases H)
    _Float16* Mh = (_Float16*)(base + 4 * MB);     // 2 MB (Moff, f16-hi)
    _Float16* Ah = (_Float16*)(base + 8 * MB);     // 2 MB
    _Float16* Al = (_Float16*)(base + 10 * MB);    // 2 MB
    _Float16* xh = (_Float16*)(base + 12 * MB);    // 8 MB (later: l1h)
    _Float16* xl = (_Float16*)(base + 20 * MB);    // 8 MB (later: l1l)
    float* r = (float*)(base + 28 * MB);           // 16 MB
    _Float16* l0h = (_Float16*)(base + 44 * MB);   // 8 MB
    _Float16* l0l = (_Float16*)(base + 52 * MB);   // 8 MB
    _Float16* l1h = xh;
    _Float16* l1l = xl;

    // ---- split A and x ----
    k_split<<<(m * dd) / 1024, 256, 0, stream>>>(A, Ah, Al);
    k_split<<<(Bn * dd) / 1024, 256, 0, stream>>>(x, xh, xl);

    // ---- H = A A^T ----
    k_mm5<0, true><<<dim3(m / 128, m / 64), 256, 0, stream>>>(
        Ah, Al, Ah, Al, dd, m, nullptr, nullptr, nullptr, H, nullptr, nullptr);

    // ---- power iteration: eta = 1.8/lambda_max(H) ----
    k_u0<<<m / 16, 256, 0, stream>>>(A, wA);
    for (int it = 0; it < 5; ++it) {
        k_pmv<<<m / 4, 256, 0, stream>>>(H, wA, wB);
        k_pmv<<<m / 4, 256, 0, stream>>>(H, wB, wA);
    }
    k_eta3<<<1, 256, 0, stream>>>(wB, wA, eta);

    // ---- Moff = -eta*H, zero diag, f16 ----
    k_makeMoff<<<(m * m) / 1024, 256, 0, stream>>>(H, eta, Mh);

    // ---- r = eta*(x A^T - b); lam0 = relu(r) split ----
    k_mm5<1, true><<<dim3(m / 128, Bn / 64), 256, 0, stream>>>(
        xh, xl, Ah, Al, dd, m, eta, b, nullptr, r, l0h, l0l);

    // ---- 29 iterations: lam <- relu(lam@Moff + (1-eta)*lam + r) ----
    const _Float16 *pih = l0h, *pil = l0l;
    _Float16 *poh = l1h, *pol = l1l;
    for (int it = 0; it < 29; ++it) {
        k_mm5<2, false><<<dim3(m / 128, Bn / 64), 256, 0, stream>>>(
            pih, pil, Mh, nullptr, m, m, eta, nullptr, r, nullptr, poh, pol);
        const _Float16* th = pih;
        const _Float16* tl = pil;
        pih = poh; pil = pol;
        poh = (_Float16*)th; pol = (_Float16*)tl;
    }
    // 29 steps: final lam in l1 (x-split no longer needed)

    // ---- A^T split into old H region; out = x - lam A ----
    k_tsplit<<<dim3(m / 32, dd / 32), 256, 0, stream>>>(A, ATh, ATl);
    k_mm5<3, true><<<dim3(dd / 128, Bn / 64), 256, 0, stream>>>(
        pih, pil, ATh, ATl, m, dd, nullptr, nullptr, x, out, nullptr, nullptr);
}

// Round 7
// 1026.132 us; speedup vs baseline: 1.1994x; 1.0127x over previous
//
#include <hip/hip_runtime.h>
#include <math.h>

// ---------------------------------------------------------------------------
// Polytope projection via dual PGD, restructured:
//   H = A A^T; eta = 1.8/lambda_max(H) (power iter)
//   Moff = -eta*H with ZERO diagonal (f16-hi; A rows unit-norm -> M_jj = 1-eta
//          exactly, applied in the epilogue)
//   r = eta*(x A^T - b); lam <- relu(lam@Moff + (1-eta)*lam + r) x29
//   out = x - lam A
// k_mm6<EPI,FB>: 128x128 block tile, 4 waves (2x2) x wave tile 64x64
// (Gm=Gn=2 frags of 32x32 -> fragment reuse 1.33 LITE / 2.0 FULL),
// mfma_f32_32x32x16_f16, BK=32 dbuf LDS, counted s_waitcnt vmcnt + raw
// s_barrier + setprio (R4-proven), XCD row-affinity block mapping
// (lam panels + Moff L2-resident per XCD). grid = (N/128, M/128), 1 block/CU.
// FULL (H, r, out): 3-MFMA Ootomo split both sides.
// LITE (iteration): 2-MFMA (lam hi+lo x Moff f16-hi) + exact diagonal.
// ---------------------------------------------------------------------------

typedef _Float16 f16x8 __attribute__((ext_vector_type(8)));
typedef _Float16 f16x4 __attribute__((ext_vector_type(4)));
typedef float f32x16 __attribute__((ext_vector_type(16)));

#define GLD16(G, L)                                                          \
  __builtin_amdgcn_global_load_lds(                                          \
      (const __attribute__((address_space(1))) void*)(const void*)(G),       \
      (__attribute__((address_space(3))) void*)(void*)(L), 16, 0, 0)

// ---------------- elementwise split kernels ----------------

__global__ __launch_bounds__(256) void k_split(const float* __restrict__ A,
                                               _Float16* __restrict__ Ah,
                                               _Float16* __restrict__ Al) {
    size_t i4 = ((size_t)blockIdx.x * 256 + threadIdx.x) * 4;
    float4 v = *(const float4*)(A + i4);
    float va[4] = {v.x, v.y, v.z, v.w};
    f16x4 hh, ll;
#pragma unroll
    for (int e = 0; e < 4; ++e) {
        _Float16 h = (_Float16)va[e];
        hh[e] = h;
        ll[e] = (_Float16)((va[e] - (float)h) * 2048.f);
    }
    *(f16x4*)(Ah + i4) = hh;
    *(f16x4*)(Al + i4) = ll;
}

// Moff = -eta*H, diag forced to 0, f16-hi only (m=1024 row length)
__global__ __launch_bounds__(256) void k_makeMoff(const float* __restrict__ H,
                                                  const float* __restrict__ eta_p,
                                                  _Float16* __restrict__ Mh) {
    float eta = eta_p[0];
    size_t i4 = ((size_t)blockIdx.x * 256 + threadIdx.x) * 4;
    float4 v = *(const float4*)(H + i4);
    float va[4] = {v.x, v.y, v.z, v.w};
    int row = (int)(i4 >> 10);
    int col0 = (int)(i4 & 1023);
    f16x4 hh;
#pragma unroll
    for (int e = 0; e < 4; ++e) {
        float mv = ((col0 + e) == row) ? 0.f : (-eta * va[e]);
        hh[e] = (_Float16)mv;
    }
    *(f16x4*)(Mh + i4) = hh;
}

// A [1024,1024] -> A^T split via 32x32 LDS tiles
__global__ __launch_bounds__(256) void k_tsplit(const float* __restrict__ A,
                                                _Float16* __restrict__ Th,
                                                _Float16* __restrict__ Tl) {
    __shared__ float ts[32][33];
    int i0 = blockIdx.x * 32, j0 = blockIdx.y * 32;
    int tr = threadIdx.x >> 3, tc4 = (threadIdx.x & 7) * 4;
    float4 v = *(const float4*)(A + (size_t)(i0 + tr) * 1024 + j0 + tc4);
    ts[tr][tc4] = v.x; ts[tr][tc4 + 1] = v.y;
    ts[tr][tc4 + 2] = v.z; ts[tr][tc4 + 3] = v.w;
    __syncthreads();
    f16x4 hh, ll;
#pragma unroll
    for (int e = 0; e < 4; ++e) {
        float x = ts[tc4 + e][tr];
        _Float16 h = (_Float16)x;
        hh[e] = h;
        ll[e] = (_Float16)((x - (float)h) * 2048.f);
    }
    *(f16x4*)(Th + (size_t)(j0 + tr) * 1024 + i0 + tc4) = hh;
    *(f16x4*)(Tl + (size_t)(j0 + tr) * 1024 + i0 + tc4) = ll;
}

// ---------------- power iteration on H ----------------

__global__ __launch_bounds__(256) void k_u0(const float* __restrict__ A,
                                            float* __restrict__ u) {
    int r = blockIdx.x * 16 + (threadIdx.x >> 4);
    int gq = threadIdx.x & 15;
    const float* ar = A + (size_t)r * 1024;
    float s = 0.f;
    for (int c = gq * 4; c < 1024; c += 64) {
        float4 v = *(const float4*)(ar + c);
        s += v.x + v.y + v.z + v.w;
    }
    s += __shfl_xor(s, 1, 16); s += __shfl_xor(s, 2, 16);
    s += __shfl_xor(s, 4, 16); s += __shfl_xor(s, 8, 16);
    if (gq == 0) u[r] = s * 0.03125f;
}

// wout = H * (win / (||win|| + 1e-12));  grid 256, 4 rows/block
__global__ __launch_bounds__(256) void k_pmv(const float* __restrict__ H,
                                             const float* __restrict__ win,
                                             float* __restrict__ wout) {
    __shared__ float red[256];
    int t = threadIdx.x;
    float4 v = *(const float4*)(win + t * 4);
    red[t] = v.x * v.x + v.y * v.y + v.z * v.z + v.w * v.w;
    __syncthreads();
    for (int o = 128; o > 0; o >>= 1) {
        if (t < o) red[t] += red[t + o];
        __syncthreads();
    }
    float inv = 1.f / (sqrtf(red[0]) + 1e-12f);
    int row = blockIdx.x * 4 + (t >> 6);
    int lane = t & 63;
    const float* hr = H + (size_t)row * 1024;
    float s = 0.f;
#pragma unroll
    for (int seg = 0; seg < 4; ++seg) {
        float4 hv = *(const float4*)(hr + seg * 256 + lane * 4);
        float4 uv = *(const float4*)(win + seg * 256 + lane * 4);
        s += hv.x * uv.x + hv.y * uv.y + hv.z * uv.z + hv.w * uv.w;
    }
#pragma unroll
    for (int k = 1; k < 64; k <<= 1) s += __shfl_xor(s, k);
    if (lane == 0) wout[row] = s * inv;
}

// eta = 1.8*(w9.w10) / ((||w9||+1e-12) * (w10.w10))
__global__ __launch_bounds__(256) void k_eta3(const float* __restrict__ w9,
                                              const float* __restrict__ w10,
                                              float* __restrict__ eta) {
    __shared__ float r99[256], r910[256], r1010[256];
    int t = threadIdx.x;
    float4 a = *(const float4*)(w9 + t * 4);
    float4 b = *(const float4*)(w10 + t * 4);
    r99[t] = a.x * a.x + a.y * a.y + a.z * a.z + a.w * a.w;
    r910[t] = a.x * b.x + a.y * b.y + a.z * b.z + a.w * b.w;
    r1010[t] = b.x * b.x + b.y * b.y + b.z * b.z + b.w * b.w;
    __syncthreads();
    for (int o = 128; o > 0; o >>= 1) {
        if (t < o) {
            r99[t] += r99[t + o];
            r910[t] += r910[t + o];
            r1010[t] += r1010[t + o];
        }
        __syncthreads();
    }
    if (t == 0)
        eta[0] = 1.8f * r910[0] / ((sqrtf(r99[0]) + 1e-12f) * r1010[0]);
}

// ---------------- fp16x2 split NT MFMA GEMM (128x128, Gm=Gn=2) ----------
// C[i][j] = sum_k Aop[i][k]*Bop[j][k].
// EPI 0: fout = acc                          (H; FB)
// EPI 1: rv = eta*(acc - b[j]) -> fout; lam0 = relu(rv) split (FB)
// EPI 2: lam = relu(acc + (1-eta)*lamin + r) split   (iteration; !FB,
//         lamin re-read from Agh/Agl at [i][j])
// EPI 3: fout = raux - acc                   (final out; raux = x; FB)

template <int EPI, bool FB>
__global__ __launch_bounds__(256, 1) void k_mm6(
    const _Float16* __restrict__ Agh, const _Float16* __restrict__ Agl,
    const _Float16* __restrict__ Bgh, const _Float16* __restrict__ Bgl,
    int Kd, int Nd,
    const float* __restrict__ eta_p, const float* __restrict__ bvec,
    const float* __restrict__ raux, float* __restrict__ fout,
    _Float16* __restrict__ lamh, _Float16* __restrict__ laml) {
    constexpr int ABYT = 16384;                   // A tile: 128 rows x 128 B
    constexpr int BBYT = FB ? 16384 : 8192;       // B tile rows: 128 B / 64 B
    constexpr int BUFB = ABYT + BBYT;
    constexpr int NB = FB ? 4 : 2;                // B gld_lds per thread
    constexpr int VM = 4 + NB;                    // loads issued per STAGE
    __shared__ __align__(16) char lds[2 * BUFB];

    const int t = threadIdx.x;
    const int wid = t >> 6, lane = t & 63;
    const int wr = wid >> 1, wc = wid & 1;        // 2x2 waves, 64x64 each
    const int l31 = lane & 31, g2 = lane >> 5;

    // XCD row-affinity bijective mapping (requires gridDim.y % 8 == 0 or ==8)
    const int gx = gridDim.x, gy = gridDim.y;
    const int id = blockIdx.x + gx * blockIdx.y;
    const int rg = gy >> 3;                       // row-tiles per XCD
    const int xcd = id & 7, rem = id >> 3;
    const int rowBase = (xcd * rg + (rem % rg)) * 128;
    const int colBase = (rem / rg) * 128;

    // ---- staging sources (pre-swizzled; LDS dest linear) ----
    // A: 128 rows x 8 slots of 16B (hi chunks 0-3, lo 4-7), slot^=(row&7)
    const _Float16* aP[4];
#pragma unroll
    for (int s = 0; s < 4; ++s) {
        int q = s * 256 + t, row = q >> 3, slot = q & 7;
        int jch = slot ^ (row & 7);
        aP[s] = (jch >= 4 ? Agl : Agh) + (size_t)(rowBase + row) * Kd +
                (jch & 3) * 8;
    }
    // B FULL: same layout as A; LITE: 128 rows x 4 slots (hi only),
    // slot ^= (row>>1)&3
    const _Float16* bP[NB];
#pragma unroll
    for (int s = 0; s < NB; ++s) {
        int q = s * 256 + t;
        if (FB) {
            int row = q >> 3, slot = q & 7;
            int jch = slot ^ (row & 7);
            bP[s] = (jch >= 4 ? Bgl : Bgh) + (size_t)(colBase + row) * Kd +
                    (jch & 3) * 8;
        } else {
            int row = q >> 2, slot = q & 3;
            int jch = slot ^ ((row >> 1) & 3);
            bP[s] = Bgh + (size_t)(colBase + row) * Kd + jch * 8;
        }
    }

#define STAGE(P, KO)                                                         \
    {                                                                        \
        _Pragma("unroll") for (int s = 0; s < 4; ++s)                        \
            GLD16(aP[s] + (KO), lds + (P)*BUFB + (s * 256 + t) * 16);        \
        _Pragma("unroll") for (int s = 0; s < NB; ++s)                       \
            GLD16(bP[s] + (KO),                                              \
                  lds + (P)*BUFB + ABYT + (s * 256 + t) * 16);               \
    }

    f32x16 acch[2][2], accm[2][2];
#pragma unroll
    for (int m2 = 0; m2 < 2; ++m2)
#pragma unroll
        for (int n2 = 0; n2 < 2; ++n2) {
            acch[m2][n2] = (f32x16)0.f;
            accm[m2][n2] = (f32x16)0.f;
        }

    STAGE(0, 0);

    const int NS = Kd >> 5;
    for (int ks = 0; ks < NS; ++ks) {
        const int p = ks & 1;
        if (ks + 1 < NS) {
            STAGE(p ^ 1, (ks + 1) << 5);
            asm volatile("s_waitcnt vmcnt(%0)" ::"i"(VM) : "memory");
        } else {
            asm volatile("s_waitcnt vmcnt(0)" ::: "memory");
        }
        asm volatile("s_barrier" ::: "memory");

        const char* ab = lds + p * BUFB;
        const char* bb = ab + ABYT;
        __builtin_amdgcn_s_setprio(1);
#pragma unroll
        for (int ksub = 0; ksub < 2; ++ksub) {
            const int j = (ksub << 1) + g2;  // hi chunk 0..3
            f16x8 ah[2], al[2], bh[2], bl[2];
#pragma unroll
            for (int m2 = 0; m2 < 2; ++m2) {
                int rowA = wr * 64 + m2 * 32 + l31;
                const char* rp = ab + rowA * 128;
                ah[m2] = *(const f16x8*)(rp + ((j ^ (rowA & 7)) << 4));
                al[m2] = *(const f16x8*)(rp + (((j + 4) ^ (rowA & 7)) << 4));
            }
#pragma unroll
            for (int n2 = 0; n2 < 2; ++n2) {
                int rowB = wc * 64 + n2 * 32 + l31;
                if (FB) {
                    const char* rp = bb + rowB * 128;
                    bh[n2] = *(const f16x8*)(rp + ((j ^ (rowB & 7)) << 4));
                    bl[n2] =
                        *(const f16x8*)(rp + (((j + 4) ^ (rowB & 7)) << 4));
                } else {
                    const char* rp = bb + rowB * 64;
                    bh[n2] =
                        *(const f16x8*)(rp + ((j ^ ((rowB >> 1) & 3)) << 4));
                }
            }
#pragma unroll
            for (int m2 = 0; m2 < 2; ++m2)
#pragma unroll
                for (int n2 = 0; n2 < 2; ++n2) {
                    acch[m2][n2] = __builtin_amdgcn_mfma_f32_32x32x16_f16(
                        ah[m2], bh[n2], acch[m2][n2], 0, 0, 0);
                    if (FB) {
                        accm[m2][n2] = __builtin_amdgcn_mfma_f32_32x32x16_f16(
                            ah[m2], bl[n2], accm[m2][n2], 0, 0, 0);
                        accm[m2][n2] = __builtin_amdgcn_mfma_f32_32x32x16_f16(
                            al[m2], bh[n2], accm[m2][n2], 0, 0, 0);
                    } else {
                        accm[m2][n2] = __builtin_amdgcn_mfma_f32_32x32x16_f16(
                            al[m2], bh[n2], accm[m2][n2], 0, 0, 0);
                    }
                }
        }
        __builtin_amdgcn_s_setprio(0);
        asm volatile("s_barrier" ::: "memory");
    }
#undef STAGE

    // ---- epilogue; C frag: col = lane&31, row = (reg&3)+8*(reg>>2)+4*g2
    const float cl = 4.8828125e-4f;  // 2^-11
    const float etav = (EPI == 1 || EPI == 2) ? eta_p[0] : 0.f;
#pragma unroll
    for (int m2 = 0; m2 < 2; ++m2)
#pragma unroll
        for (int n2 = 0; n2 < 2; ++n2) {
            const int col = colBase + wc * 64 + n2 * 32 + l31;
#pragma unroll
            for (int reg = 0; reg < 16; ++reg) {
                const int row = rowBase + wr * 64 + m2 * 32 + (reg & 3) +
                                ((reg >> 2) << 3) + (g2 << 2);
                const size_t idx = (size_t)row * Nd + col;
                float val = acch[m2][n2][reg] + accm[m2][n2][reg] * cl;
                if (EPI == 0) {
                    fout[idx] = val;
                } else if (EPI == 1) {
                    float rv = etav * (val - bvec[col]);
                    fout[idx] = rv;
                    float lv = fmaxf(rv, 0.f);
                    _Float16 h = (_Float16)lv;
                    lamh[idx] = h;
                    laml[idx] = (_Float16)((lv - (float)h) * 2048.f);
                } else if (EPI == 2) {
                    float li = (float)Agh[idx] + (float)Agl[idx] * cl;
                    float lv = fmaxf(val + (1.f - etav) * li + raux[idx], 0.f);
                    _Float16 h = (_Float16)lv;
                    lamh[idx] = h;
                    laml[idx] = (_Float16)((lv - (float)h) * 2048.f);
                } else {
                    fout[idx] = raux[idx] - val;
                }
            }
        }
}

// ---------------------------------------------------------------------------

extern "C" void kernel_launch(void* const* d_in, const int* in_sizes, int n_in,
                              void* d_out, int out_size, void* d_ws, size_t ws_size,
                              hipStream_t stream) {
    const float* x = (const float*)d_in[0];  // [B, d] = [4096, 1024]
    const float* A = (const float*)d_in[1];  // [m, d] = [1024, 1024]
    const float* b = (const float*)d_in[2];  // [m]

    const int m = in_sizes[2];           // 1024
    const int dd = in_sizes[1] / m;      // 1024
    const int Bn = in_sizes[0] / dd;     // 4096
    float* out = (float*)d_out;

    // workspace layout (x-split region reused as l1; H reused for A^T split)
    const size_t MB = 1u << 20;
    char* w8 = (char*)d_ws;
    float* eta = (float*)w8;                       // 256 B
    float* wA = (float*)(w8 + 256);                // 4 KB
    float* wB = (float*)(w8 + 256 + 4096);         // 4 KB
    char* base = w8 + 16384;
    float* H = (float*)base;                       // 4 MB (later: AT split)
    _Float16* ATh = (_Float16*)base;               //   2 MB (aliases H)
    _Float16* ATl = (_Float16*)(base + 2 * MB);    //   2 MB (aliases H)
    _Float16* Mh = (_Float16*)(base + 4 * MB);     // 2 MB (Moff, f16-hi)
    _Float16* Ah = (_Float16*)(base + 8 * MB);     // 2 MB
    _Float16* Al = (_Float16*)(base + 10 * MB);    // 2 MB
    _Float16* xh = (_Float16*)(base + 12 * MB);    // 8 MB (later: l1h)
    _Float16* xl = (_Float16*)(base + 20 * MB);    // 8 MB (later: l1l)
    float* r = (float*)(base + 28 * MB);           // 16 MB
    _Float16* l0h = (_Float16*)(base + 44 * MB);   // 8 MB
    _Float16* l0l = (_Float16*)(base + 52 * MB);   // 8 MB
    _Float16* l1h = xh;
    _Float16* l1l = xl;

    // ---- split A and x ----
    k_split<<<(m * dd) / 1024, 256, 0, stream>>>(A, Ah, Al);
    k_split<<<(Bn * dd) / 1024, 256, 0, stream>>>(x, xh, xl);

    // ---- H = A A^T ----
    k_mm6<0, true><<<dim3(m / 128, m / 128), 256, 0, stream>>>(
        Ah, Al, Ah, Al, dd, m, nullptr, nullptr, nullptr, H, nullptr, nullptr);

    // ---- power iteration: eta = 1.8/lambda_max(H) ----
    k_u0<<<m / 16, 256, 0, stream>>>(A, wA);
    for (int it = 0; it < 5; ++it) {
        k_pmv<<<m / 4, 256, 0, stream>>>(H, wA, wB);
        k_pmv<<<m / 4, 256, 0, stream>>>(H, wB, wA);
    }
    k_eta3<<<1, 256, 0, stream>>>(wB, wA, eta);

    // ---- Moff = -eta*H, zero diag, f16 ----
    k_makeMoff<<<(m * m) / 1024, 256, 0, stream>>>(H, eta, Mh);

    // ---- r = eta*(x A^T - b); lam0 = relu(r) split ----
    k_mm6<1, true><<<dim3(m / 128, Bn / 128), 256, 0, stream>>>(
        xh, xl, Ah, Al, dd, m, eta, b, nullptr, r, l0h, l0l);

    // ---- 29 iterations: lam <- relu(lam@Moff + (1-eta)*lam + r) ----
    const _Float16 *pih = l0h, *pil = l0l;
    _Float16 *poh = l1h, *pol = l1l;
    for (int it = 0; it < 29; ++it) {
        k_mm6<2, false><<<dim3(m / 128, Bn / 128), 256, 0, stream>>>(
            pih, pil, Mh, nullptr, m, m, eta, nullptr, r, nullptr, poh, pol);
        const _Float16* th = pih;
        const _Float16* tl = pil;
        pih = poh; pil = pol;
        poh = (_Float16*)th; pol = (_Float16*)tl;
    }
    // 29 steps: final lam in l1 (x-split no longer needed)

    // ---- A^T split into old H region; out = x - lam A ----
    k_tsplit<<<dim3(m / 32, dd / 32), 256, 0, stream>>>(A, ATh, ATl);
    k_mm6<3, true><<<dim3(dd / 128, Bn / 128), 256, 0, stream>>>(
        pih, pil, ATh, ATl, m, dd, nullptr, nullptr, x, out, nullptr, nullptr);
}

// Round 8
// 751.313 us; speedup vs baseline: 1.6381x; 1.3658x over previous
//
#include <hip/hip_runtime.h>
#include <math.h>

// ---------------------------------------------------------------------------
// Polytope projection via dual PGD, restructured:
//   H = A A^T (full fp16x2 split GEMM); eta = 1.8/lambda_max(H) (power iter)
//   Moff = -eta*H, ZERO diag, f16 (A rows unit-norm -> M_jj = 1-eta exact)
//   r = eta*(x A^T - b) (full split GEMM) -> stored f16-hi
//   lam <- relu(lam@Moff + (1-eta)*lam + r) x29, lam stored f16-hi ONLY
//     -> iteration GEMM is 1 MFMA per product, tiles/traffic halved
//   out = x - lam A   (lam_h x split-A^T, 2 MFMA)
// k_mm7<EPI,AS,BS>: 128x128 tile, 4 waves (2x2) x 64x64 wave tile,
// mfma_f32_32x32x16_f16, BK=32 dbuf LDS, counted vmcnt + raw s_barrier +
// setprio (R4-proven), XCD row-affinity mapping. AS/BS = f16 components.
// ---------------------------------------------------------------------------

typedef _Float16 f16x8 __attribute__((ext_vector_type(8)));
typedef _Float16 f16x4 __attribute__((ext_vector_type(4)));
typedef float f32x16 __attribute__((ext_vector_type(16)));

#define GLD16(G, L)                                                          \
  __builtin_amdgcn_global_load_lds(                                          \
      (const __attribute__((address_space(1))) void*)(const void*)(G),       \
      (__attribute__((address_space(3))) void*)(void*)(L), 16, 0, 0)

// ---------------- elementwise split kernels ----------------

__global__ __launch_bounds__(256) void k_split(const float* __restrict__ A,
                                               _Float16* __restrict__ Ah,
                                               _Float16* __restrict__ Al) {
    size_t i4 = ((size_t)blockIdx.x * 256 + threadIdx.x) * 4;
    float4 v = *(const float4*)(A + i4);
    float va[4] = {v.x, v.y, v.z, v.w};
    f16x4 hh, ll;
#pragma unroll
    for (int e = 0; e < 4; ++e) {
        _Float16 h = (_Float16)va[e];
        hh[e] = h;
        ll[e] = (_Float16)((va[e] - (float)h) * 2048.f);
    }
    *(f16x4*)(Ah + i4) = hh;
    *(f16x4*)(Al + i4) = ll;
}

// Moff = -eta*H, diag forced to 0, f16-hi only (m=1024 row length)
__global__ __launch_bounds__(256) void k_makeMoff(const float* __restrict__ H,
                                                  const float* __restrict__ eta_p,
                                                  _Float16* __restrict__ Mh) {
    float eta = eta_p[0];
    size_t i4 = ((size_t)blockIdx.x * 256 + threadIdx.x) * 4;
    float4 v = *(const float4*)(H + i4);
    float va[4] = {v.x, v.y, v.z, v.w};
    int row = (int)(i4 >> 10);
    int col0 = (int)(i4 & 1023);
    f16x4 hh;
#pragma unroll
    for (int e = 0; e < 4; ++e) {
        float mv = ((col0 + e) == row) ? 0.f : (-eta * va[e]);
        hh[e] = (_Float16)mv;
    }
    *(f16x4*)(Mh + i4) = hh;
}

// A [1024,1024] -> A^T split via 32x32 LDS tiles
__global__ __launch_bounds__(256) void k_tsplit(const float* __restrict__ A,
                                                _Float16* __restrict__ Th,
                                                _Float16* __restrict__ Tl) {
    __shared__ float ts[32][33];
    int i0 = blockIdx.x * 32, j0 = blockIdx.y * 32;
    int tr = threadIdx.x >> 3, tc4 = (threadIdx.x & 7) * 4;
    float4 v = *(const float4*)(A + (size_t)(i0 + tr) * 1024 + j0 + tc4);
    ts[tr][tc4] = v.x; ts[tr][tc4 + 1] = v.y;
    ts[tr][tc4 + 2] = v.z; ts[tr][tc4 + 3] = v.w;
    __syncthreads();
    f16x4 hh, ll;
#pragma unroll
    for (int e = 0; e < 4; ++e) {
        float x = ts[tc4 + e][tr];
        _Float16 h = (_Float16)x;
        hh[e] = h;
        ll[e] = (_Float16)((x - (float)h) * 2048.f);
    }
    *(f16x4*)(Th + (size_t)(j0 + tr) * 1024 + i0 + tc4) = hh;
    *(f16x4*)(Tl + (size_t)(j0 + tr) * 1024 + i0 + tc4) = ll;
}

// ---------------- power iteration on H ----------------

__global__ __launch_bounds__(256) void k_u0(const float* __restrict__ A,
                                            float* __restrict__ u) {
    int r = blockIdx.x * 16 + (threadIdx.x >> 4);
    int gq = threadIdx.x & 15;
    const float* ar = A + (size_t)r * 1024;
    float s = 0.f;
    for (int c = gq * 4; c < 1024; c += 64) {
        float4 v = *(const float4*)(ar + c);
        s += v.x + v.y + v.z + v.w;
    }
    s += __shfl_xor(s, 1, 16); s += __shfl_xor(s, 2, 16);
    s += __shfl_xor(s, 4, 16); s += __shfl_xor(s, 8, 16);
    if (gq == 0) u[r] = s * 0.03125f;
}

// wout = H * (win / (||win|| + 1e-12));  grid 256, 4 rows/block
__global__ __launch_bounds__(256) void k_pmv(const float* __restrict__ H,
                                             const float* __restrict__ win,
                                             float* __restrict__ wout) {
    __shared__ float red[256];
    int t = threadIdx.x;
    float4 v = *(const float4*)(win + t * 4);
    red[t] = v.x * v.x + v.y * v.y + v.z * v.z + v.w * v.w;
    __syncthreads();
    for (int o = 128; o > 0; o >>= 1) {
        if (t < o) red[t] += red[t + o];
        __syncthreads();
    }
    float inv = 1.f / (sqrtf(red[0]) + 1e-12f);
    int row = blockIdx.x * 4 + (t >> 6);
    int lane = t & 63;
    const float* hr = H + (size_t)row * 1024;
    float s = 0.f;
#pragma unroll
    for (int seg = 0; seg < 4; ++seg) {
        float4 hv = *(const float4*)(hr + seg * 256 + lane * 4);
        float4 uv = *(const float4*)(win + seg * 256 + lane * 4);
        s += hv.x * uv.x + hv.y * uv.y + hv.z * uv.z + hv.w * uv.w;
    }
#pragma unroll
    for (int k = 1; k < 64; k <<= 1) s += __shfl_xor(s, k);
    if (lane == 0) wout[row] = s * inv;
}

// eta = 1.8*(w9.w10) / ((||w9||+1e-12) * (w10.w10))
__global__ __launch_bounds__(256) void k_eta3(const float* __restrict__ w9,
                                              const float* __restrict__ w10,
                                              float* __restrict__ eta) {
    __shared__ float r99[256], r910[256], r1010[256];
    int t = threadIdx.x;
    float4 a = *(const float4*)(w9 + t * 4);
    float4 b = *(const float4*)(w10 + t * 4);
    r99[t] = a.x * a.x + a.y * a.y + a.z * a.z + a.w * a.w;
    r910[t] = a.x * b.x + a.y * b.y + a.z * b.z + a.w * b.w;
    r1010[t] = b.x * b.x + b.y * b.y + b.z * b.z + b.w * b.w;
    __syncthreads();
    for (int o = 128; o > 0; o >>= 1) {
        if (t < o) {
            r99[t] += r99[t + o];
            r910[t] += r910[t + o];
            r1010[t] += r1010[t + o];
        }
        __syncthreads();
    }
    if (t == 0)
        eta[0] = 1.8f * r910[0] / ((sqrtf(r99[0]) + 1e-12f) * r1010[0]);
}

// ---------------- unified split NT MFMA GEMM (128x128, Gm=Gn=2) ----------
// C[i][j] = sum_k Aop[i][k]*Bop[j][k];  AS/BS = # f16 components (1|2).
// EPI 0: fout = acc                                (H; 2,2)
// EPI 1: rv = eta*(acc - b[j]); rhout=(f16)rv; outh=relu16(rv)   (2,2)
// EPI 2: outh = relu16(acc + (1-eta)*lamin + rh)   (iteration; 1,1;
//        lamin re-read from Agh at [i][j])
// EPI 3: fout = xaux - acc                         (final out; 1,2)

template <int EPI, int AS, int BS>
__global__ __launch_bounds__(256, ((AS + BS) > 2 ? 1 : 2)) void k_mm7(
    const _Float16* __restrict__ Agh, const _Float16* __restrict__ Agl,
    const _Float16* __restrict__ Bgh, const _Float16* __restrict__ Bgl,
    int Kd, int Nd,
    const float* __restrict__ eta_p, const float* __restrict__ bvec,
    const _Float16* __restrict__ rh, const float* __restrict__ xaux,
    float* __restrict__ fout, _Float16* __restrict__ outh,
    _Float16* __restrict__ rhout) {
    constexpr int AROW = 64 * AS;                 // bytes per A-tile row
    constexpr int BROW = 64 * BS;                 // bytes per B-tile row
    constexpr int ABYT = 128 * AROW;
    constexpr int BBYT = 128 * BROW;
    constexpr int BUFB = ABYT + BBYT;
    constexpr int NA = 2 * AS, NB = 2 * BS;       // gld_lds per thread
    constexpr int VM = NA + NB;                   // loads per STAGE
    __shared__ __align__(16) char lds[2 * BUFB];

    const int t = threadIdx.x;
    const int wid = t >> 6, lane = t & 63;
    const int wr = wid >> 1, wc = wid & 1;        // 2x2 waves, 64x64 each
    const int l31 = lane & 31, g2 = lane >> 5;

    // XCD row-affinity bijective mapping (gridDim.y = 8 or 32)
    const int gx = gridDim.x, gy = gridDim.y;
    const int id = blockIdx.x + gx * blockIdx.y;
    const int rg = gy >> 3;
    const int xcd = id & 7, rem = id >> 3;
    const int rowBase = (xcd * rg + (rem % rg)) * 128;
    const int colBase = (rem / rg) * 128;

    // ---- staging sources (pre-swizzled; LDS dest linear) ----
    const _Float16* aP[NA];
#pragma unroll
    for (int s = 0; s < NA; ++s) {
        int q = s * 256 + t;
        if (AS == 2) {
            int row = q >> 3, slot = q & 7, jch = slot ^ (row & 7);
            aP[s] = (jch >= 4 ? Agl : Agh) + (size_t)(rowBase + row) * Kd +
                    (jch & 3) * 8;
        } else {
            int row = q >> 2, slot = q & 3, jch = slot ^ ((row >> 1) & 3);
            aP[s] = Agh + (size_t)(rowBase + row) * Kd + jch * 8;
        }
    }
    const _Float16* bP[NB];
#pragma unroll
    for (int s = 0; s < NB; ++s) {
        int q = s * 256 + t;
        if (BS == 2) {
            int row = q >> 3, slot = q & 7, jch = slot ^ (row & 7);
            bP[s] = (jch >= 4 ? Bgl : Bgh) + (size_t)(colBase + row) * Kd +
                    (jch & 3) * 8;
        } else {
            int row = q >> 2, slot = q & 3, jch = slot ^ ((row >> 1) & 3);
            bP[s] = Bgh + (size_t)(colBase + row) * Kd + jch * 8;
        }
    }

#define STAGE(P, KO)                                                         \
    {                                                                        \
        _Pragma("unroll") for (int s = 0; s < NA; ++s)                       \
            GLD16(aP[s] + (KO), lds + (P)*BUFB + (s * 256 + t) * 16);        \
        _Pragma("unroll") for (int s = 0; s < NB; ++s)                       \
            GLD16(bP[s] + (KO),                                              \
                  lds + (P)*BUFB + ABYT + (s * 256 + t) * 16);               \
    }

    f32x16 acch[2][2], accm[2][2];
#pragma unroll
    for (int m2 = 0; m2 < 2; ++m2)
#pragma unroll
        for (int n2 = 0; n2 < 2; ++n2) {
            acch[m2][n2] = (f32x16)0.f;
            if constexpr (AS + BS > 2) accm[m2][n2] = (f32x16)0.f;
        }

    STAGE(0, 0);

    const int NS = Kd >> 5;
    for (int ks = 0; ks < NS; ++ks) {
        const int p = ks & 1;
        if (ks + 1 < NS) {
            STAGE(p ^ 1, (ks + 1) << 5);
            asm volatile("s_waitcnt vmcnt(%0)" ::"i"(VM) : "memory");
        } else {
            asm volatile("s_waitcnt vmcnt(0)" ::: "memory");
        }
        asm volatile("s_barrier" ::: "memory");

        const char* ab = lds + p * BUFB;
        const char* bb = ab + ABYT;
        __builtin_amdgcn_s_setprio(1);
#pragma unroll
        for (int ksub = 0; ksub < 2; ++ksub) {
            const int j = (ksub << 1) + g2;  // hi chunk 0..3
            f16x8 ah[2], al[2], bh[2], bl[2];
#pragma unroll
            for (int m2 = 0; m2 < 2; ++m2) {
                int rowA = wr * 64 + m2 * 32 + l31;
                const char* rp = ab + rowA * AROW;
                if (AS == 2) {
                    ah[m2] = *(const f16x8*)(rp + ((j ^ (rowA & 7)) << 4));
                    al[m2] =
                        *(const f16x8*)(rp + (((j + 4) ^ (rowA & 7)) << 4));
                } else {
                    ah[m2] =
                        *(const f16x8*)(rp + ((j ^ ((rowA >> 1) & 3)) << 4));
                }
            }
#pragma unroll
            for (int n2 = 0; n2 < 2; ++n2) {
                int rowB = wc * 64 + n2 * 32 + l31;
                const char* rp = bb + rowB * BROW;
                if (BS == 2) {
                    bh[n2] = *(const f16x8*)(rp + ((j ^ (rowB & 7)) << 4));
                    bl[n2] =
                        *(const f16x8*)(rp + (((j + 4) ^ (rowB & 7)) << 4));
                } else {
                    bh[n2] =
                        *(const f16x8*)(rp + ((j ^ ((rowB >> 1) & 3)) << 4));
                }
            }
#pragma unroll
            for (int m2 = 0; m2 < 2; ++m2)
#pragma unroll
                for (int n2 = 0; n2 < 2; ++n2) {
                    acch[m2][n2] = __builtin_amdgcn_mfma_f32_32x32x16_f16(
                        ah[m2], bh[n2], acch[m2][n2], 0, 0, 0);
                    if constexpr (BS == 2)
                        accm[m2][n2] = __builtin_amdgcn_mfma_f32_32x32x16_f16(
                            ah[m2], bl[n2], accm[m2][n2], 0, 0, 0);
                    if constexpr (AS == 2)
                        accm[m2][n2] = __builtin_amdgcn_mfma_f32_32x32x16_f16(
                            al[m2], bh[n2], accm[m2][n2], 0, 0, 0);
                }
        }
        __builtin_amdgcn_s_setprio(0);
        asm volatile("s_barrier" ::: "memory");
    }
#undef STAGE

    // ---- epilogue; C frag: col = lane&31, row = (reg&3)+8*(reg>>2)+4*g2
    const float cl = 4.8828125e-4f;  // 2^-11
    const float etav = (EPI == 1 || EPI == 2) ? eta_p[0] : 0.f;
#pragma unroll
    for (int m2 = 0; m2 < 2; ++m2)
#pragma unroll
        for (int n2 = 0; n2 < 2; ++n2) {
            const int col = colBase + wc * 64 + n2 * 32 + l31;
#pragma unroll
            for (int reg = 0; reg < 16; ++reg) {
                const int row = rowBase + wr * 64 + m2 * 32 + (reg & 3) +
                                ((reg >> 2) << 3) + (g2 << 2);
                const size_t idx = (size_t)row * Nd + col;
                float val = acch[m2][n2][reg];
                if constexpr (AS + BS > 2) val += accm[m2][n2][reg] * cl;
                if (EPI == 0) {
                    fout[idx] = val;
                } else if (EPI == 1) {
                    float rv = etav * (val - bvec[col]);
                    rhout[idx] = (_Float16)rv;
                    outh[idx] = (_Float16)fmaxf(rv, 0.f);
                } else if (EPI == 2) {
                    float lv = fmaxf(val + (1.f - etav) * (float)Agh[idx] +
                                         (float)rh[idx],
                                     0.f);
                    outh[idx] = (_Float16)lv;
                } else {
                    fout[idx] = xaux[idx] - val;
                }
            }
        }
}

// ---------------------------------------------------------------------------

extern "C" void kernel_launch(void* const* d_in, const int* in_sizes, int n_in,
                              void* d_out, int out_size, void* d_ws, size_t ws_size,
                              hipStream_t stream) {
    const float* x = (const float*)d_in[0];  // [B, d] = [4096, 1024]
    const float* A = (const float*)d_in[1];  // [m, d] = [1024, 1024]
    const float* b = (const float*)d_in[2];  // [m]

    const int m = in_sizes[2];           // 1024
    const int dd = in_sizes[1] / m;      // 1024
    const int Bn = in_sizes[0] / dd;     // 4096
    float* out = (float*)d_out;

    // workspace layout (~42 MB): xh reused as l1h after r-GEMM;
    // H reused for A^T split after Moff is built.
    const size_t MB = 1u << 20;
    char* w8 = (char*)d_ws;
    float* eta = (float*)w8;                       // 256 B
    float* wA = (float*)(w8 + 256);                // 4 KB
    float* wB = (float*)(w8 + 256 + 4096);         // 4 KB
    char* base = w8 + 16384;
    float* H = (float*)base;                       // 4 MB (later: AT split)
    _Float16* ATh = (_Float16*)base;               //   2 MB (aliases H)
    _Float16* ATl = (_Float16*)(base + 2 * MB);    //   2 MB (aliases H)
    _Float16* Mh = (_Float16*)(base + 4 * MB);     // 2 MB (Moff f16)
    _Float16* Ah = (_Float16*)(base + 6 * MB);     // 2 MB
    _Float16* Al = (_Float16*)(base + 8 * MB);     // 2 MB
    _Float16* xh = (_Float16*)(base + 10 * MB);    // 8 MB (later: l1h)
    _Float16* xl = (_Float16*)(base + 18 * MB);    // 8 MB
    _Float16* rhb = (_Float16*)(base + 26 * MB);   // 8 MB (r f16-hi)
    _Float16* l0h = (_Float16*)(base + 34 * MB);   // 8 MB
    _Float16* l1h = xh;

    // ---- split A and x ----
    k_split<<<(m * dd) / 1024, 256, 0, stream>>>(A, Ah, Al);
    k_split<<<(Bn * dd) / 1024, 256, 0, stream>>>(x, xh, xl);

    // ---- H = A A^T (full split) ----
    k_mm7<0, 2, 2><<<dim3(m / 128, m / 128), 256, 0, stream>>>(
        Ah, Al, Ah, Al, dd, m, nullptr, nullptr, nullptr, nullptr, H,
        nullptr, nullptr);

    // ---- power iteration: eta = 1.8/lambda_max(H) ----
    k_u0<<<m / 16, 256, 0, stream>>>(A, wA);
    for (int it = 0; it < 5; ++it) {
        k_pmv<<<m / 4, 256, 0, stream>>>(H, wA, wB);
        k_pmv<<<m / 4, 256, 0, stream>>>(H, wB, wA);
    }
    k_eta3<<<1, 256, 0, stream>>>(wB, wA, eta);

    // ---- Moff = -eta*H, zero diag, f16 ----
    k_makeMoff<<<(m * m) / 1024, 256, 0, stream>>>(H, eta, Mh);

    // ---- r = eta*(x A^T - b) -> f16-hi; lam0 = relu16(r) ----
    k_mm7<1, 2, 2><<<dim3(m / 128, Bn / 128), 256, 0, stream>>>(
        xh, xl, Ah, Al, dd, m, eta, b, nullptr, nullptr, nullptr, l0h, rhb);

    // ---- 29 iterations: lam <- relu(lam@Moff + (1-eta)*lam + r) ----
    const _Float16* pih = l0h;
    _Float16* poh = l1h;
    for (int it = 0; it < 29; ++it) {
        k_mm7<2, 1, 1><<<dim3(m / 128, Bn / 128), 256, 0, stream>>>(
            pih, nullptr, Mh, nullptr, m, m, eta, nullptr, rhb, nullptr,
            nullptr, poh, nullptr);
        const _Float16* th = pih;
        pih = poh;
        poh = (_Float16*)th;
    }
    // 29 steps (odd): final lam in l1h == pih

    // ---- A^T split into old H region; out = x - lam A ----
    k_tsplit<<<dim3(m / 32, dd / 32), 256, 0, stream>>>(A, ATh, ATl);
    k_mm7<3, 1, 2><<<dim3(dd / 128, Bn / 128), 256, 0, stream>>>(
        pih, nullptr, ATh, ATl, m, dd, nullptr, nullptr, nullptr, x, out,
        nullptr, nullptr);
}